// Round 8
// baseline (413.758 us; speedup 1.0000x reference)
//
#include <hip/hip_runtime.h>

#define DEV __device__ __forceinline__

typedef short bf16x8 __attribute__((ext_vector_type(8)));
typedef float f32x4  __attribute__((ext_vector_type(4)));
typedef unsigned short ushort_t;

// L=577, BT=128, D=768, B=16, T=8, H=W=24, CM=192, CR=48, K=3, M=L*BT=73856

DEV unsigned short f2bf(float f) {
  unsigned u = __float_as_uint(f);
  unsigned r = (u + 0x7fffu + ((u >> 16) & 1u)) >> 16;
  return (unsigned short)r;
}

DEV unsigned cvt_pk_bf16(float a, float b) {   // {lo:bf16(a), hi:bf16(b)} RNE
  unsigned r;
  asm("v_cvt_pk_bf16_f32 %0, %1, %2" : "=v"(r) : "v"(a), "v"(b));
  return r;
}

DEV float bf2f(unsigned short b) { return __uint_as_float((unsigned)b << 16); }

DEV float silu_g(float v) { return v / (1.f + __expf(-1.702f * v)); }

// load 8 consecutive fp32, convert to bf16x8 fragment
DEV bf16x8 loadA_cvt(const float* p) {
  float4 v0 = *(const float4*)p;
  float4 v1 = *(const float4*)(p + 4);
  int4 w;
  w.x = (int)cvt_pk_bf16(v0.x, v0.y);
  w.y = (int)cvt_pk_bf16(v0.z, v0.w);
  w.z = (int)cvt_pk_bf16(v1.x, v1.y);
  w.w = (int)cvt_pk_bf16(v1.z, v1.w);
  return __builtin_bit_cast(bf16x8, w);
}

// ---------------------------------------------------------------------------
// Weight prep: transpose + cast to bf16, K-contiguous rows for MFMA B frags.
// ---------------------------------------------------------------------------
__global__ __launch_bounds__(256)
void prep_kernel(const float* __restrict__ w_pre, const float* __restrict__ w_proj,
                 short* __restrict__ w_preT, short* __restrict__ w_projT) {
  int i = blockIdx.x * 256 + threadIdx.x;
  if (i < 192 * 768) {
    int n = i / 768, k = i - n * 768;
    w_preT[i] = (short)f2bf(w_pre[k * 192 + n]);
    int n2 = i / 192, k2 = i - n2 * 192;
    w_projT[i] = (short)f2bf(w_proj[k2 * 768 + n2]);
  }
}

// ---------------------------------------------------------------------------
// GEMM1, LDS-free streaming: h(bf16)[M x 192] = x(f32)[M x 768] @ w_preT + b
// BM=128, BN=192(full N), 512 thr = 8 waves (2M x 4N), wave tile 64x48.
// Each lane loads its MFMA fragments directly from global:
//   A: 32 B/lane (wave = 16 rows x 128 B contiguous), cvt_pk -> bf16
//   B: 16 B/lane from w_preT (288 KB, L2-resident for all blocks)
// No barriers: waves free-run, compiler pipelines the 24 K-chunks.
// mfma(B_frag, A_frag): reg-axis = 4 consecutive N cols -> packed stores.
// ---------------------------------------------------------------------------
__global__ __launch_bounds__(512, 3)
void gemm1_kernel(const float* __restrict__ Af, const short* __restrict__ Bt,
                  const float* __restrict__ bias, ushort_t* __restrict__ C) {
  constexpr int KTOT = 768, NTOT = 192, BM = 128;
  const int tid = threadIdx.x;
  const int wave = tid >> 6, lane = tid & 63;
  const int m0 = blockIdx.x * BM;
  const int wm = wave >> 2, wn = wave & 3;
  const int lr = lane & 15, lk8 = lane >> 4;

  const float* aBase[4];
  const short* bBase[3];
  #pragma unroll
  for (int fm = 0; fm < 4; ++fm)
    aBase[fm] = Af + (size_t)(m0 + wm * 64 + fm * 16 + lr) * KTOT + lk8 * 8;
  #pragma unroll
  for (int fn = 0; fn < 3; ++fn)
    bBase[fn] = Bt + (size_t)(wn * 48 + fn * 16 + lr) * KTOT + lk8 * 8;

  f32x4 acc[4][3] = {};

  #pragma unroll 4
  for (int kt = 0; kt < KTOT; kt += 32) {   // one 32-k chunk per MFMA
    bf16x8 af[4], bf[3];
    #pragma unroll
    for (int fm = 0; fm < 4; ++fm) af[fm] = loadA_cvt(aBase[fm] + kt);
    #pragma unroll
    for (int fn = 0; fn < 3; ++fn) bf[fn] = *(const bf16x8*)(bBase[fn] + kt);
    #pragma unroll
    for (int fm = 0; fm < 4; ++fm)
      #pragma unroll
      for (int fn = 0; fn < 3; ++fn)
        acc[fm][fn] = __builtin_amdgcn_mfma_f32_16x16x32_bf16(
            bf[fn], af[fm], acc[fm][fn], 0, 0, 0);
  }

  // epilogue: packed bf16 stores (reg-axis = 4 consecutive N cols)
  const int cb = (lane >> 4) * 4;
  #pragma unroll
  for (int fm = 0; fm < 4; ++fm) {
    int row = m0 + wm * 64 + fm * 16 + lr;
    #pragma unroll
    for (int fn = 0; fn < 3; ++fn) {
      int col = wn * 48 + fn * 16 + cb;
      float4 bv = *(const float4*)(bias + col);
      int2 w;
      w.x = (int)cvt_pk_bf16(acc[fm][fn][0] + bv.x, acc[fm][fn][1] + bv.y);
      w.y = (int)cvt_pk_bf16(acc[fm][fn][2] + bv.z, acc[fm][fn][3] + bv.w);
      *(int2*)&C[(size_t)row * NTOT + col] = w;
    }
  }
}

// ---------------------------------------------------------------------------
// GEMM2, LDS-free streaming: out(f32)[M x 768] = s(bf16)[M x 192] @ w_projT+b
// Same geometry; A is bf16 (direct 16 B fragment loads); 6 K-chunks.
// s (28 MB) re-read by 4 N-block-columns -> L3-resident. NT stores for out.
// ---------------------------------------------------------------------------
__global__ __launch_bounds__(512, 4)
void gemm2_kernel(const short* __restrict__ Ab, const short* __restrict__ Bt,
                  const float* __restrict__ bias, float* __restrict__ C) {
  constexpr int KTOT = 192, NTOT = 768, BM = 128;
  const int tid = threadIdx.x;
  const int wave = tid >> 6, lane = tid & 63;
  const int m0 = blockIdx.x * BM;
  const int n0 = blockIdx.y * 192;
  const int wm = wave >> 2, wn = wave & 3;
  const int lr = lane & 15, lk8 = lane >> 4;

  const short* aBase[4];
  const short* bBase[3];
  #pragma unroll
  for (int fm = 0; fm < 4; ++fm)
    aBase[fm] = Ab + (size_t)(m0 + wm * 64 + fm * 16 + lr) * KTOT + lk8 * 8;
  #pragma unroll
  for (int fn = 0; fn < 3; ++fn)
    bBase[fn] = Bt + (size_t)(n0 + wn * 48 + fn * 16 + lr) * KTOT + lk8 * 8;

  f32x4 acc[4][3] = {};

  #pragma unroll
  for (int kt = 0; kt < KTOT; kt += 32) {
    bf16x8 af[4], bf[3];
    #pragma unroll
    for (int fm = 0; fm < 4; ++fm) af[fm] = *(const bf16x8*)(aBase[fm] + kt);
    #pragma unroll
    for (int fn = 0; fn < 3; ++fn) bf[fn] = *(const bf16x8*)(bBase[fn] + kt);
    #pragma unroll
    for (int fm = 0; fm < 4; ++fm)
      #pragma unroll
      for (int fn = 0; fn < 3; ++fn)
        acc[fm][fn] = __builtin_amdgcn_mfma_f32_16x16x32_bf16(
            bf[fn], af[fm], acc[fm][fn], 0, 0, 0);
  }

  // epilogue: f32x4 nontemporal stores
  const int cb = (lane >> 4) * 4;
  #pragma unroll
  for (int fm = 0; fm < 4; ++fm) {
    int row = m0 + wm * 64 + fm * 16 + lr;
    #pragma unroll
    for (int fn = 0; fn < 3; ++fn) {
      int col = n0 + wn * 48 + fn * 16 + cb;
      float4 bv = *(const float4*)(bias + col);
      f32x4 o;
      o[0] = acc[fm][fn][0] + bv.x;
      o[1] = acc[fm][fn][1] + bv.y;
      o[2] = acc[fm][fn][2] + bv.z;
      o[3] = acc[fm][fn][3] + bv.w;
      __builtin_nontemporal_store(o, (f32x4*)&C[(size_t)row * NTOT + col]);
    }
  }
}

// ---------------------------------------------------------------------------
// d[bt][c] = mean over l=1..576 of h_bf16[(l*128+bt)*192 + c]
// grid 128, 384 thr: 16 slices x 36 l's, bf16x8 loads, LDS slice-reduce.
// ---------------------------------------------------------------------------
__global__ __launch_bounds__(384)
void reduce_d_kernel(const ushort_t* __restrict__ h, float* __restrict__ d) {
  const int bt = blockIdx.x, tid = threadIdx.x;
  const int slice = tid / 24, c8 = tid % 24;
  __shared__ float part[16][192];
  float sum[8] = {};
  #pragma unroll 4
  for (int i = 0; i < 36; ++i) {
    int l = 1 + slice * 36 + i;
    bf16x8 v = *(const bf16x8*)&h[((size_t)l * 128 + bt) * 192 + c8 * 8];
    #pragma unroll
    for (int j = 0; j < 8; ++j) sum[j] += bf2f((unsigned short)v[j]);
  }
  #pragma unroll
  for (int j = 0; j < 8; ++j) part[slice][c8 * 8 + j] = sum[j];
  __syncthreads();
  if (tid < 192) {
    float s = 0.f;
    #pragma unroll
    for (int sl = 0; sl < 16; ++sl) s += part[sl][tid];
    d[bt * 192 + tid] = s * (1.f / 576.f);
  }
}

// ---------------------------------------------------------------------------
// Small path: w_g AND w_a staged up front; w_b staged concurrently with the
// a-conv compute phase. One block per b, 256 thr.
// ---------------------------------------------------------------------------
__global__ __launch_bounds__(256)
void small_path_kernel(const float* __restrict__ d,
                       const float* __restrict__ w_g, const float* __restrict__ b_g,
                       const float* __restrict__ w_a, const float* __restrict__ b_a,
                       const float* __restrict__ w_b,
                       float* __restrict__ alpha) {
  const int b = blockIdx.x, tid = threadIdx.x;
  __shared__ unsigned short wg_buf[36864];   // 72 KB (w_g, then w_b)
  __shared__ unsigned short wa_buf[27648];   // 54 KB
  __shared__ float e[8][192];
  __shared__ float md[192];
  __shared__ float a[8][48];

  // ---- stage w_g + w_a + load d ----
  #pragma unroll
  for (int it = 0; it < 36; ++it) {
    int i = tid + it * 256;
    float4 v = *(const float4*)(w_g + i * 4);
    int2 w;
    w.x = (int)cvt_pk_bf16(v.x, v.y);
    w.y = (int)cvt_pk_bf16(v.z, v.w);
    *(int2*)&wg_buf[i * 4] = w;
  }
  #pragma unroll
  for (int it = 0; it < 27; ++it) {
    int i = tid + it * 256;
    float4 v = *(const float4*)(w_a + i * 4);
    int2 w;
    w.x = (int)cvt_pk_bf16(v.x, v.y);
    w.y = (int)cvt_pk_bf16(v.z, v.w);
    *(int2*)&wa_buf[i * 4] = w;
  }
  for (int i = tid; i < 384; i += 256)
    *(float4*)((float*)e + i * 4) = *(const float4*)(d + (size_t)b * 1536 + i * 4);
  __syncthreads();

  // ---- md = mean over t ----
  if (tid < 192) {
    float m = 0.f;
    #pragma unroll
    for (int t = 0; t < 8; ++t) m += e[t][tid];
    md[tid] = m * 0.125f;
  }
  __syncthreads();

  // ---- g = md @ w_g + b_g; e += g ----
  if (tid < 192) {
    float accg = b_g[tid];
    #pragma unroll 8
    for (int k = 0; k < 192; ++k)
      accg += md[k] * bf2f(wg_buf[k * 192 + tid]);
    #pragma unroll
    for (int t = 0; t < 8; ++t) e[t][tid] += accg;
  }
  __syncthreads();   // e final; wg_buf dead

  // ---- stage w_b (into wg_buf) CONCURRENT with a = relu(conv1d(e, w_a)) ----
  #pragma unroll
  for (int it = 0; it < 27; ++it) {
    int i = tid + it * 256;
    float4 v = *(const float4*)(w_b + i * 4);
    int2 w;
    w.x = (int)cvt_pk_bf16(v.x, v.y);
    w.y = (int)cvt_pk_bf16(v.z, v.w);
    *(int2*)&wg_buf[i * 4] = w;
  }
  for (int o = tid; o < 384; o += 256) {
    int t = o / 48, r = o - t * 48;
    float acc = b_a[r];
    #pragma unroll
    for (int dt = 0; dt < 3; ++dt) {
      int tt = t + dt - 1;
      if ((unsigned)tt < 8u) {
        #pragma unroll 8
        for (int k = 0; k < 192; ++k)
          acc += e[tt][k] * bf2f(wa_buf[(dt * 192 + k) * 48 + r]);
      }
    }
    a[t][r] = fmaxf(acc, 0.f);
  }
  __syncthreads();

  // ---- alpha = conv1d(a, w_b) + 1 ----
  if (tid < 192) {
    #pragma unroll
    for (int t = 0; t < 8; ++t) {
      float acc = 1.0f;
      #pragma unroll
      for (int dt = 0; dt < 3; ++dt) {
        int tt = t + dt - 1;
        if ((unsigned)tt < 8u) {
          #pragma unroll 8
          for (int r = 0; r < 48; ++r)
            acc += a[tt][r] * bf2f(wg_buf[(dt * 48 + r) * 192 + tid]);
        }
      }
      alpha[(size_t)(b * 8 + t) * 192 + tid] = acc;
    }
  }
}

// ---------------------------------------------------------------------------
// Depthwise 3x3 conv + alpha scale + b_conv + cls passthrough + SiLU -> s(bf16)
// ---------------------------------------------------------------------------
__global__ __launch_bounds__(256)
void dwconv_silu_kernel(const ushort_t* __restrict__ h, const float* __restrict__ alpha,
                        const float* __restrict__ w_base, const float* __restrict__ b_conv,
                        ushort_t* __restrict__ s) {
  const int bt = blockIdx.x, c0 = blockIdx.y * 32;
  const int tid = threadIdx.x;
  __shared__ ushort_t tile[576][32];   // 36 KB

  #pragma unroll
  for (int it = 0; it < 9; ++it) {
    int gidx = tid + it * 256;
    int p = gidx >> 2, cc = (gidx & 3) * 8;
    *(bf16x8*)&tile[p][cc] =
        *(const bf16x8*)&h[((size_t)(1 + p) * 128 + bt) * 192 + c0 + cc];
  }

  const int c = tid & 31;
  const int prow = tid >> 5;
  float wv[3][3];
  #pragma unroll
  for (int dh = 0; dh < 3; ++dh)
    #pragma unroll
    for (int dw = 0; dw < 3; ++dw)
      wv[dh][dw] = w_base[(dh * 3 + dw) * 192 + c0 + c];
  const float av = alpha[bt * 192 + c0 + c];
  const float bc = b_conv[c0 + c];

  if (tid < 32) {
    float v = bf2f(h[(size_t)bt * 192 + c0 + tid]);
    s[(size_t)bt * 192 + c0 + tid] = f2bf(silu_g(v));
  }
  __syncthreads();

  for (int i = 0; i < 72; ++i) {
    int p = prow + i * 8;
    int hh = p / 24, ww = p - hh * 24;
    float acc = 0.f;
    #pragma unroll
    for (int dh = 0; dh < 3; ++dh) {
      int y = hh + dh - 1;
      if ((unsigned)y >= 24u) continue;
      #pragma unroll
      for (int dw = 0; dw < 3; ++dw) {
        int xx = ww + dw - 1;
        if ((unsigned)xx >= 24u) continue;
        acc += bf2f(tile[y * 24 + xx][c]) * wv[dh][dw];
      }
    }
    float pre = acc * av + bc;
    s[(size_t)((1 + p) * 128 + bt) * 192 + c0 + c] = f2bf(silu_g(pre));
  }
}

// ---------------------------------------------------------------------------
extern "C" void kernel_launch(void* const* d_in, const int* in_sizes, int n_in,
                              void* d_out, int out_size, void* d_ws, size_t ws_size,
                              hipStream_t stream) {
  (void)in_sizes; (void)n_in; (void)out_size; (void)ws_size;
  const float* x      = (const float*)d_in[0];
  const float* w_pre  = (const float*)d_in[1];
  const float* b_pre  = (const float*)d_in[2];
  const float* w_base = (const float*)d_in[3];
  const float* b_conv = (const float*)d_in[4];
  const float* w_g    = (const float*)d_in[5];
  const float* b_g    = (const float*)d_in[6];
  const float* w_a    = (const float*)d_in[7];
  const float* b_a    = (const float*)d_in[8];
  const float* w_b    = (const float*)d_in[9];
  const float* w_proj = (const float*)d_in[10];
  const float* b_proj = (const float*)d_in[11];

  float* out = (float*)d_out;
  ushort_t* h = (ushort_t*)d_out;         // h bf16 (28 MB) in front of out;
                                          // consumed before GEMM2 overwrites.
  char* ws = (char*)d_ws;
  short* w_preT  = (short*)(ws);                  //      0: 294912 B
  short* w_projT = (short*)(ws + 294912);         // 294912: 294912 B
  float* dbuf    = (float*)(ws + 589824);         // 589824:  98304 B
  float* alpha   = (float*)(ws + 688128);         // 688128:  98304 B
  short* s       = (short*)(ws + 786432);         // 28360704 B

  prep_kernel<<<576, 256, 0, stream>>>(w_pre, w_proj, w_preT, w_projT);

  // GEMM1: h(bf16) = x @ w_pre + b_pre   (M=73856, K=768, N=192)
  gemm1_kernel<<<577, 512, 0, stream>>>(x, w_preT, b_pre, h);

  reduce_d_kernel<<<128, 384, 0, stream>>>(h, dbuf);
  small_path_kernel<<<16, 256, 0, stream>>>(dbuf, w_g, b_g, w_a, b_a, w_b, alpha);
  dwconv_silu_kernel<<<dim3(128, 6), 256, 0, stream>>>(h, alpha, w_base, b_conv,
                                                       (ushort_t*)s);

  // GEMM2: out = s @ w_proj + b_proj   (M=73856, K=192, N=768)
  gemm2_kernel<<<dim3(577, 4), 512, 0, stream>>>((const short*)s, w_projT,
                                                 b_proj, out);
}

// Round 9
// 241.323 us; speedup vs baseline: 1.7145x; 1.7145x over previous
//
#include <hip/hip_runtime.h>

#define DEV __device__ __forceinline__

typedef short bf16x8 __attribute__((ext_vector_type(8)));
typedef float f32x4  __attribute__((ext_vector_type(4)));
typedef unsigned short ushort_t;

// L=577, BT=128, D=768, B=16, T=8, H=W=24, CM=192, CR=48, K=3, M=L*BT=73856

DEV unsigned short f2bf(float f) {
  unsigned u = __float_as_uint(f);
  unsigned r = (u + 0x7fffu + ((u >> 16) & 1u)) >> 16;
  return (unsigned short)r;
}

DEV unsigned cvt_pk_bf16(float a, float b) {   // {lo:bf16(a), hi:bf16(b)} RNE
  unsigned r;
  asm("v_cvt_pk_bf16_f32 %0, %1, %2" : "=v"(r) : "v"(a), "v"(b));
  return r;
}

DEV float bf2f(unsigned short b) { return __uint_as_float((unsigned)b << 16); }

DEV float silu_g(float v) { return v / (1.f + __expf(-1.702f * v)); }

DEV void gload_lds16(const void* g, void* l) {
  __builtin_amdgcn_global_load_lds(
      (const __attribute__((address_space(1))) unsigned int*)g,
      (__attribute__((address_space(3))) unsigned int*)l, 16, 0, 0);
}

// ---------------------------------------------------------------------------
// Weight prep: transpose + cast to bf16, K-contiguous rows for MFMA B frags.
// ---------------------------------------------------------------------------
__global__ __launch_bounds__(256)
void prep_kernel(const float* __restrict__ w_pre, const float* __restrict__ w_proj,
                 short* __restrict__ w_preT, short* __restrict__ w_projT) {
  int i = blockIdx.x * 256 + threadIdx.x;
  if (i < 192 * 768) {
    int n = i / 768, k = i - n * 768;
    w_preT[i] = (short)f2bf(w_pre[k * 192 + n]);
    int n2 = i / 192, k2 = i - n2 * 192;
    w_projT[i] = (short)f2bf(w_proj[k2 * 768 + n2]);
  }
}

// ---------------------------------------------------------------------------
// GEMM1 (R7 structure): h(bf16)[M x 192] = x(f32)[M x 768] @ w_preT + b_pre
// BM=128, BN=192(full), BK=64, 512 thr = 8 waves (2M x 4N), wave tile 64x48.
// Double-buffered, counted s_waitcnt; XOR chunk swizzle (chunk ^= row&7).
// mfma(B_frag, A_frag): reg-axis = 4 consecutive N cols -> packed bf16 stores.
// ---------------------------------------------------------------------------
__global__ __launch_bounds__(512, 4)
void gemm1_kernel(const float* __restrict__ Af, const short* __restrict__ Bt,
                  const float* __restrict__ bias, ushort_t* __restrict__ C) {
  constexpr int BM = 128, BK = 64, KTOT = 768, NTOT = 192, NT = 12;
  __shared__ short As[2][BM * BK];   // 2x16 KB
  __shared__ short Bs[2][192 * BK];  // 2x24 KB

  const int tid  = threadIdx.x;
  const int wave = tid >> 6, lane = tid & 63;
  const int m0 = blockIdx.x * BM;
  const int wm = wave >> 2, wn = wave & 3;
  const int lr  = lane & 15;
  const int lk8 = lane >> 4;
  const int srow = lane >> 3;
  const int schunk = lane & 7;

  f32x4 acc[4][3] = {};
  float4 areg[2][2];

  auto loadA_f32 = [&](int kt) {
    #pragma unroll
    for (int s = 0; s < 2; ++s) {
      int id = tid + s * 512;
      int r = id >> 3, c = id & 7;
      int cg = c ^ (r & 7);
      const float* p = Af + (size_t)(m0 + r) * KTOT + kt + cg * 8;
      areg[s][0] = *(const float4*)p;
      areg[s][1] = *(const float4*)(p + 4);
    }
  };
  auto cvtStoreA = [&](int buf) {
    #pragma unroll
    for (int s = 0; s < 2; ++s) {
      int id = tid + s * 512;
      int r = id >> 3, c = id & 7;
      int4 w;
      w.x = (int)cvt_pk_bf16(areg[s][0].x, areg[s][0].y);
      w.y = (int)cvt_pk_bf16(areg[s][0].z, areg[s][0].w);
      w.z = (int)cvt_pk_bf16(areg[s][1].x, areg[s][1].y);
      w.w = (int)cvt_pk_bf16(areg[s][1].z, areg[s][1].w);
      *(int4*)&As[buf][r * 64 + c * 8] = w;
    }
  };
  auto stageB = [&](int kt, int buf) {
    #pragma unroll
    for (int j = 0; j < 3; ++j) {
      int rb8 = wave * 3 + j;
      int r = rb8 * 8 + srow;
      const short* src = Bt + (size_t)r * KTOT + kt + (schunk ^ srow) * 8;
      gload_lds16(src, (char*)Bs[buf] + rb8 * 1024);
    }
  };
  auto compute = [&](int buf) {
    #pragma unroll
    for (int ks = 0; ks < 2; ++ks) {
      int kc = ks * 4 + lk8;
      bf16x8 af[4], bfv[3];
      #pragma unroll
      for (int fm = 0; fm < 4; ++fm) {
        int row = wm * 64 + fm * 16 + lr;
        af[fm] = *(const bf16x8*)&As[buf][row * 64 + (kc ^ (row & 7)) * 8];
      }
      #pragma unroll
      for (int fn = 0; fn < 3; ++fn) {
        int row = wn * 48 + fn * 16 + lr;
        bfv[fn] = *(const bf16x8*)&Bs[buf][row * 64 + (kc ^ (row & 7)) * 8];
      }
      #pragma unroll
      for (int fm = 0; fm < 4; ++fm)
        #pragma unroll
        for (int fn = 0; fn < 3; ++fn)
          acc[fm][fn] = __builtin_amdgcn_mfma_f32_16x16x32_bf16(
              bfv[fn], af[fm], acc[fm][fn], 0, 0, 0);
    }
  };

  // prologue
  loadA_f32(0);
  cvtStoreA(0);
  stageB(0, 0);                 // 3 vm (oldest)
  loadA_f32(BK);                // 4 vm (tile 1)
  asm volatile("s_waitcnt vmcnt(4) lgkmcnt(0)" ::: "memory");
  __builtin_amdgcn_s_barrier();

  #pragma unroll
  for (int t = 0; t < NT; ++t) {
    const int cur = t & 1, nxt = cur ^ 1;
    if (t + 1 < NT) {
      stageB((t + 1) * BK, nxt);
      cvtStoreA(nxt);
      if (t + 2 < NT) loadA_f32((t + 2) * BK);
    }
    compute(cur);
    if (t + 1 < NT) {
      if (t + 2 < NT)
        asm volatile("s_waitcnt vmcnt(4) lgkmcnt(0)" ::: "memory");
      else
        asm volatile("s_waitcnt vmcnt(0) lgkmcnt(0)" ::: "memory");
      __builtin_amdgcn_s_barrier();
    }
  }

  const int cb = (lane >> 4) * 4;
  #pragma unroll
  for (int fm = 0; fm < 4; ++fm) {
    int row = m0 + wm * 64 + fm * 16 + lr;
    #pragma unroll
    for (int fn = 0; fn < 3; ++fn) {
      int col = wn * 48 + fn * 16 + cb;
      float4 bv = *(const float4*)(bias + col);
      int2 w;
      w.x = (int)cvt_pk_bf16(acc[fm][fn][0] + bv.x, acc[fm][fn][1] + bv.y);
      w.y = (int)cvt_pk_bf16(acc[fm][fn][2] + bv.z, acc[fm][fn][3] + bv.w);
      *(int2*)&C[(size_t)row * NTOT + col] = w;
    }
  }
}

// ---------------------------------------------------------------------------
// d[bt][c] = mean over l=1..576 of h_bf16[(l*128+bt)*192 + c]
// ---------------------------------------------------------------------------
__global__ __launch_bounds__(384)
void reduce_d_kernel(const ushort_t* __restrict__ h, float* __restrict__ d) {
  const int bt = blockIdx.x, tid = threadIdx.x;
  const int slice = tid / 24, c8 = tid % 24;
  __shared__ float part[16][192];
  float sum[8] = {};
  #pragma unroll 4
  for (int i = 0; i < 36; ++i) {
    int l = 1 + slice * 36 + i;
    bf16x8 v = *(const bf16x8*)&h[((size_t)l * 128 + bt) * 192 + c8 * 8];
    #pragma unroll
    for (int j = 0; j < 8; ++j) sum[j] += bf2f((unsigned short)v[j]);
  }
  #pragma unroll
  for (int j = 0; j < 8; ++j) part[slice][c8 * 8 + j] = sum[j];
  __syncthreads();
  if (tid < 192) {
    float s = 0.f;
    #pragma unroll
    for (int sl = 0; sl < 16; ++sl) s += part[sl][tid];
    d[bt * 192 + tid] = s * (1.f / 576.f);
  }
}

// ---------------------------------------------------------------------------
// Small path: w_g AND w_a staged up front; w_b staged concurrently with the
// a-conv compute phase. One block per b, 256 thr.
// ---------------------------------------------------------------------------
__global__ __launch_bounds__(256)
void small_path_kernel(const float* __restrict__ d,
                       const float* __restrict__ w_g, const float* __restrict__ b_g,
                       const float* __restrict__ w_a, const float* __restrict__ b_a,
                       const float* __restrict__ w_b,
                       float* __restrict__ alpha) {
  const int b = blockIdx.x, tid = threadIdx.x;
  __shared__ unsigned short wg_buf[36864];   // 72 KB (w_g, then w_b)
  __shared__ unsigned short wa_buf[27648];   // 54 KB
  __shared__ float e[8][192];
  __shared__ float md[192];
  __shared__ float a[8][48];

  #pragma unroll
  for (int it = 0; it < 36; ++it) {
    int i = tid + it * 256;
    float4 v = *(const float4*)(w_g + i * 4);
    int2 w;
    w.x = (int)cvt_pk_bf16(v.x, v.y);
    w.y = (int)cvt_pk_bf16(v.z, v.w);
    *(int2*)&wg_buf[i * 4] = w;
  }
  #pragma unroll
  for (int it = 0; it < 27; ++it) {
    int i = tid + it * 256;
    float4 v = *(const float4*)(w_a + i * 4);
    int2 w;
    w.x = (int)cvt_pk_bf16(v.x, v.y);
    w.y = (int)cvt_pk_bf16(v.z, v.w);
    *(int2*)&wa_buf[i * 4] = w;
  }
  for (int i = tid; i < 384; i += 256)
    *(float4*)((float*)e + i * 4) = *(const float4*)(d + (size_t)b * 1536 + i * 4);
  __syncthreads();

  if (tid < 192) {
    float m = 0.f;
    #pragma unroll
    for (int t = 0; t < 8; ++t) m += e[t][tid];
    md[tid] = m * 0.125f;
  }
  __syncthreads();

  if (tid < 192) {
    float accg = b_g[tid];
    #pragma unroll 8
    for (int k = 0; k < 192; ++k)
      accg += md[k] * bf2f(wg_buf[k * 192 + tid]);
    #pragma unroll
    for (int t = 0; t < 8; ++t) e[t][tid] += accg;
  }
  __syncthreads();   // e final; wg_buf dead

  #pragma unroll
  for (int it = 0; it < 27; ++it) {
    int i = tid + it * 256;
    float4 v = *(const float4*)(w_b + i * 4);
    int2 w;
    w.x = (int)cvt_pk_bf16(v.x, v.y);
    w.y = (int)cvt_pk_bf16(v.z, v.w);
    *(int2*)&wg_buf[i * 4] = w;
  }
  for (int o = tid; o < 384; o += 256) {
    int t = o / 48, r = o - t * 48;
    float acc = b_a[r];
    #pragma unroll
    for (int dt = 0; dt < 3; ++dt) {
      int tt = t + dt - 1;
      if ((unsigned)tt < 8u) {
        #pragma unroll 8
        for (int k = 0; k < 192; ++k)
          acc += e[tt][k] * bf2f(wa_buf[(dt * 192 + k) * 48 + r]);
      }
    }
    a[t][r] = fmaxf(acc, 0.f);
  }
  __syncthreads();

  if (tid < 192) {
    #pragma unroll
    for (int t = 0; t < 8; ++t) {
      float acc = 1.0f;
      #pragma unroll
      for (int dt = 0; dt < 3; ++dt) {
        int tt = t + dt - 1;
        if ((unsigned)tt < 8u) {
          #pragma unroll 8
          for (int r = 0; r < 48; ++r)
            acc += a[tt][r] * bf2f(wg_buf[(dt * 48 + r) * 192 + tid]);
        }
      }
      alpha[(size_t)(b * 8 + t) * 192 + tid] = acc;
    }
  }
}

// ---------------------------------------------------------------------------
// FUSED dwconv+SiLU+GEMM2: out[M x 768] = silu(dwconv(h)*alpha+b_conv) @ w_projT
// One block per l (577 blocks, 512 thr = 8 waves). Phase 1: compute the
// 128x192 s-tile (bf16) into LDS (dwconv over h's 9 neighbor positions, or
// cls passthrough for blk 0). Phase 2: loop 4 N-chunks of 192: stage full
// B-chunk (72 KB) via gload_lds (inverse-swizzled source), 3 K-tiles of
// MFMA, NT f32x4 stores. s never touches HBM. LDS = 48+72 = 120 KB.
// ---------------------------------------------------------------------------
__global__ __launch_bounds__(512, 2)
void fused_out_kernel(const ushort_t* __restrict__ h, const float* __restrict__ alpha,
                      const float* __restrict__ w_base, const float* __restrict__ b_conv,
                      const short* __restrict__ Bt, const float* __restrict__ bias,
                      float* __restrict__ out) {
  constexpr int KTOT = 192, NTOT = 768;
  __shared__ ushort_t Stile[128 * 192];   // 49152 B (swizzled 16B chunks)
  __shared__ short    Btile[192 * 192];   // 73728 B (swizzled 16B chunks)

  const int tid  = threadIdx.x;
  const int blk  = blockIdx.x;            // = l
  const int wave = tid >> 6, lane = tid & 63;
  const int wm = wave >> 2, wn = wave & 3;
  const int lr = lane & 15, lk8 = lane >> 4;

  // ---- phase 1: s-tile (row = bt, col = c) ----
  const int row = tid >> 2;               // 0..127
  const int cg  = tid & 3;
  if (blk == 0) {
    #pragma unroll
    for (int j = 0; j < 6; ++j) {
      int c8 = cg + 4 * j;
      bf16x8 hv = *(const bf16x8*)&h[(size_t)row * 192 + c8 * 8];
      int4 pk;
      float v0 = silu_g(bf2f((ushort_t)hv[0])), v1 = silu_g(bf2f((ushort_t)hv[1]));
      float v2 = silu_g(bf2f((ushort_t)hv[2])), v3 = silu_g(bf2f((ushort_t)hv[3]));
      float v4 = silu_g(bf2f((ushort_t)hv[4])), v5 = silu_g(bf2f((ushort_t)hv[5]));
      float v6 = silu_g(bf2f((ushort_t)hv[6])), v7 = silu_g(bf2f((ushort_t)hv[7]));
      pk.x = (int)cvt_pk_bf16(v0, v1); pk.y = (int)cvt_pk_bf16(v2, v3);
      pk.z = (int)cvt_pk_bf16(v4, v5); pk.w = (int)cvt_pk_bf16(v6, v7);
      int chp = (c8 & ~7) | ((c8 & 7) ^ (row & 7));
      *(int4*)&Stile[row * 192 + chp * 8] = pk;
    }
  } else {
    const int p = blk - 1, hh = p / 24, ww = p - hh * 24;
    #pragma unroll
    for (int j = 0; j < 6; ++j) {
      int c8 = cg + 4 * j;
      int cbase = c8 * 8;
      float acc8[8] = {};
      #pragma unroll
      for (int dh = 0; dh < 3; ++dh) {
        int y = hh + dh - 1;
        if ((unsigned)y >= 24u) continue;       // wave-uniform
        #pragma unroll
        for (int dw = 0; dw < 3; ++dw) {
          int xx = ww + dw - 1;
          if ((unsigned)xx >= 24u) continue;    // wave-uniform
          bf16x8 hv = *(const bf16x8*)
              &h[((size_t)(1 + y * 24 + xx) * 128 + row) * 192 + cbase];
          const float* wp = w_base + (dh * 3 + dw) * 192 + cbase;
          float4 w0 = *(const float4*)wp, w1 = *(const float4*)(wp + 4);
          acc8[0] += bf2f((ushort_t)hv[0]) * w0.x;
          acc8[1] += bf2f((ushort_t)hv[1]) * w0.y;
          acc8[2] += bf2f((ushort_t)hv[2]) * w0.z;
          acc8[3] += bf2f((ushort_t)hv[3]) * w0.w;
          acc8[4] += bf2f((ushort_t)hv[4]) * w1.x;
          acc8[5] += bf2f((ushort_t)hv[5]) * w1.y;
          acc8[6] += bf2f((ushort_t)hv[6]) * w1.z;
          acc8[7] += bf2f((ushort_t)hv[7]) * w1.w;
        }
      }
      const float* ap = alpha + (size_t)row * 192 + cbase;
      float4 a0 = *(const float4*)ap, a1 = *(const float4*)(ap + 4);
      const float* bp = b_conv + cbase;
      float4 c0 = *(const float4*)bp, c1 = *(const float4*)(bp + 4);
      float v0 = silu_g(acc8[0] * a0.x + c0.x), v1 = silu_g(acc8[1] * a0.y + c0.y);
      float v2 = silu_g(acc8[2] * a0.z + c0.z), v3 = silu_g(acc8[3] * a0.w + c0.w);
      float v4 = silu_g(acc8[4] * a1.x + c1.x), v5 = silu_g(acc8[5] * a1.y + c1.y);
      float v6 = silu_g(acc8[6] * a1.z + c1.z), v7 = silu_g(acc8[7] * a1.w + c1.w);
      int4 pk;
      pk.x = (int)cvt_pk_bf16(v0, v1); pk.y = (int)cvt_pk_bf16(v2, v3);
      pk.z = (int)cvt_pk_bf16(v4, v5); pk.w = (int)cvt_pk_bf16(v6, v7);
      int chp = (c8 & ~7) | ((c8 & 7) ^ (row & 7));
      *(int4*)&Stile[row * 192 + chp * 8] = pk;
    }
  }

  // ---- phase 2: 4 N-chunks of 192 ----
  #pragma unroll 1
  for (int nc = 0; nc < 4; ++nc) {
    const int n0 = nc * 192;
    __syncthreads();   // s-tile writes visible (nc=0) / prev B reads done

    // stage B chunk: 4608 16B slots; wave w owns rows [w*24, w*24+24)
    #pragma unroll
    for (int i = 0; i < 9; ++i) {
      int q = wave * 576 + i * 64 + lane;       // per-lane slot
      int brow = q / 24;
      int ch = q - brow * 24;
      int ach = (ch & ~7) | ((ch & 7) ^ (brow & 7));   // inverse-swizzle source
      const short* src = Bt + (size_t)(n0 + brow) * KTOT + ach * 8;
      gload_lds16(src, (char*)Btile + (wave * 9 + i) * 1024);
    }
    asm volatile("s_waitcnt vmcnt(0)" ::: "memory");
    __builtin_amdgcn_s_barrier();

    f32x4 acc[4][3] = {};
    #pragma unroll
    for (int kt = 0; kt < 3; ++kt) {
      #pragma unroll
      for (int ks = 0; ks < 2; ++ks) {
        int kc = kt * 8 + ks * 4 + lk8;         // chunk 0..23
        bf16x8 af[4], bfv[3];
        #pragma unroll
        for (int fm = 0; fm < 4; ++fm) {
          int sr = wm * 64 + fm * 16 + lr;
          int chp = (kc & ~7) | ((kc & 7) ^ (sr & 7));
          af[fm] = *(const bf16x8*)&Stile[sr * 192 + chp * 8];
        }
        #pragma unroll
        for (int fn = 0; fn < 3; ++fn) {
          int br = wn * 48 + fn * 16 + lr;
          int chp = (kc & ~7) | ((kc & 7) ^ (br & 7));
          bfv[fn] = *(const bf16x8*)&Btile[br * 192 + chp * 8];
        }
        #pragma unroll
        for (int fm = 0; fm < 4; ++fm)
          #pragma unroll
          for (int fn = 0; fn < 3; ++fn)
            acc[fm][fn] = __builtin_amdgcn_mfma_f32_16x16x32_bf16(
                bfv[fn], af[fm], acc[fm][fn], 0, 0, 0);
      }
    }

    // stores: reg-axis = 4 consecutive N cols
    const int cb = (lane >> 4) * 4;
    #pragma unroll
    for (int fm = 0; fm < 4; ++fm) {
      int orow = blk * 128 + wm * 64 + fm * 16 + lr;
      #pragma unroll
      for (int fn = 0; fn < 3; ++fn) {
        int col = n0 + wn * 48 + fn * 16 + cb;
        float4 bv = *(const float4*)(bias + col);
        f32x4 o;
        o[0] = acc[fm][fn][0] + bv.x;
        o[1] = acc[fm][fn][1] + bv.y;
        o[2] = acc[fm][fn][2] + bv.z;
        o[3] = acc[fm][fn][3] + bv.w;
        __builtin_nontemporal_store(o, (f32x4*)&out[(size_t)orow * NTOT + col]);
      }
    }
  }
}

// ---------------------------------------------------------------------------
extern "C" void kernel_launch(void* const* d_in, const int* in_sizes, int n_in,
                              void* d_out, int out_size, void* d_ws, size_t ws_size,
                              hipStream_t stream) {
  (void)in_sizes; (void)n_in; (void)out_size; (void)ws_size;
  const float* x      = (const float*)d_in[0];
  const float* w_pre  = (const float*)d_in[1];
  const float* b_pre  = (const float*)d_in[2];
  const float* w_base = (const float*)d_in[3];
  const float* b_conv = (const float*)d_in[4];
  const float* w_g    = (const float*)d_in[5];
  const float* b_g    = (const float*)d_in[6];
  const float* w_a    = (const float*)d_in[7];
  const float* b_a    = (const float*)d_in[8];
  const float* w_b    = (const float*)d_in[9];
  const float* w_proj = (const float*)d_in[10];
  const float* b_proj = (const float*)d_in[11];

  float* out = (float*)d_out;
  char* ws = (char*)d_ws;
  short* w_preT  = (short*)(ws);                  //      0: 294912 B
  short* w_projT = (short*)(ws + 294912);         // 294912: 294912 B
  float* dbuf    = (float*)(ws + 589824);         // 589824:  98304 B
  float* alpha   = (float*)(ws + 688128);         // 688128:  98304 B
  ushort_t* h    = (ushort_t*)(ws + 786432);      // h bf16: 28360704 B
  // h in ws (NOT d_out): fused kernel reads h neighbors while writing out.

  prep_kernel<<<576, 256, 0, stream>>>(w_pre, w_proj, w_preT, w_projT);

  // GEMM1: h(bf16) = x @ w_pre + b_pre   (M=73856, K=768, N=192)
  gemm1_kernel<<<577, 512, 0, stream>>>(x, w_preT, b_pre, h);

  reduce_d_kernel<<<128, 384, 0, stream>>>(h, dbuf);
  small_path_kernel<<<16, 256, 0, stream>>>(dbuf, w_g, b_g, w_a, b_a, w_b, alpha);

  // fused dwconv+SiLU+GEMM2: out = silu(dwconv(h)*alpha+b_conv) @ w_proj + b
  fused_out_kernel<<<577, 512, 0, stream>>>(h, alpha, w_base, b_conv,
                                            w_projT, b_proj, out);
}